// Round 4
// baseline (1873.948 us; speedup 1.0000x reference)
//
#include <hip/hip_runtime.h>
#include <stdint.h>

#define N_TOT 32768
#define DDIM  512
#define KCB   8192
#define GBN   128                   // rows per block in gemm_topk
#define MARGIN 0.15f
#define RPARTS 32
#define RROWS  (KCB / RPARTS)       // 256 cb rows per part (1 per thread)
#define RGRID  8192                 // 256 slots x 32 parts

typedef _Float16 half8 __attribute__((ext_vector_type(8)));
typedef float    floatx4 __attribute__((ext_vector_type(4)));

// ---------------- async global->LDS 16B ----------------
typedef const __attribute__((address_space(1))) unsigned int* gas_ptr;
typedef __attribute__((address_space(3))) unsigned int* las_ptr;
__device__ __forceinline__ void gld_lds16(void* l, const void* g) {
    __builtin_amdgcn_global_load_lds((gas_ptr)g, (las_ptr)l, 16, 0, 0);
}

// ---------------- convert x to fp16 ----------------
__global__ __launch_bounds__(256) void convert_x_kernel(
    const float* __restrict__ x, _Float16* __restrict__ xh) {
    size_t i = ((size_t)blockIdx.x * 256 + threadIdx.x) * 8;
    float4 v0 = *(const float4*)(x + i);
    float4 v1 = *(const float4*)(x + i + 4);
    half8 h;
    h[0] = (_Float16)v0.x; h[1] = (_Float16)v0.y; h[2] = (_Float16)v0.z; h[3] = (_Float16)v0.w;
    h[4] = (_Float16)v1.x; h[5] = (_Float16)v1.y; h[6] = (_Float16)v1.z; h[7] = (_Float16)v1.w;
    *(half8*)(xh + i) = h;
}

// ---------------- convert codebook to fp16 + fp32 norms (one wave/row) ----------------
__global__ __launch_bounds__(256) void convert_cb_kernel(
    const float* __restrict__ cb, _Float16* __restrict__ cbh, float* __restrict__ cnorm) {
    int row = blockIdx.x * 4 + (threadIdx.x >> 6);
    int lane = threadIdx.x & 63;
    const float* src = cb + (size_t)row * DDIM + lane * 8;
    float4 v0 = *(const float4*)src;
    float4 v1 = *(const float4*)(src + 4);
    half8 h;
    h[0] = (_Float16)v0.x; h[1] = (_Float16)v0.y; h[2] = (_Float16)v0.z; h[3] = (_Float16)v0.w;
    h[4] = (_Float16)v1.x; h[5] = (_Float16)v1.y; h[6] = (_Float16)v1.z; h[7] = (_Float16)v1.w;
    *(half8*)(cbh + (size_t)row * DDIM + lane * 8) = h;
    float s = v0.x*v0.x + v0.y*v0.y + v0.z*v0.z + v0.w*v0.w
            + v1.x*v1.x + v1.y*v1.y + v1.z*v1.z + v1.w*v1.w;
#pragma unroll
    for (int off = 32; off > 0; off >>= 1) s += __shfl_down(s, off, 64);
    if (lane == 0) cnorm[row] = s;
}

// ---------------- A-resident barrier-free MFMA GEMM + top-2 argmin ----------------
// Block: 512 threads = 8 waves. A tile (128 rows x 512 d, fp16) staged once in LDS.
// Wave (half, wq): rows [half*64, half*64+64), coltile-groups gi = g*4+wq.
// B fragments loaded straight from global (L2/L3-resident) -- no barriers in K-loop.
__global__ __launch_bounds__(512, 2) void gemm_topk_kernel(
    const _Float16* __restrict__ xh, const _Float16* __restrict__ cbh,
    const float* __restrict__ cnorm,
    int* __restrict__ indices, int* __restrict__ flags,
    int* __restrict__ list, int* __restrict__ count,
    unsigned long long* __restrict__ result) {

    __shared__ __align__(16) char smem[131072];   // 128 KB: A tile, then merge scratch
    _Float16* As = (_Float16*)smem;

    const int tid = threadIdx.x;
    const int wave = tid >> 6, lane = tid & 63;
    const int l15 = lane & 15, quad = lane >> 4;
    const int half = wave >> 2, wq = wave & 3;
    const int row0 = blockIdx.x * GBN;

    // ---- stage A once: row r = i*8 + wave; chunk-swizzled (chunk c stored at c^(r&7)) ----
#pragma unroll
    for (int i = 0; i < 16; ++i) {
        int r = i * 8 + wave;
        gld_lds16(As + (size_t)r * 512,
                  xh + (((size_t)(row0 + r)) << 9) + (lane ^ (r & 7)) * 8);
    }
    __syncthreads();   // compiler drains vmcnt before barrier

    float b1[16], b2[16];
    int   i1[16];
#pragma unroll
    for (int s = 0; s < 16; ++s) { b1[s] = 3.402823466e38f; b2[s] = 3.402823466e38f; i1[s] = 0; }

    for (int g = 0; g < 32; ++g) {
        const int ct0 = (g * 4 + wq) * 4;     // 4 coltiles of 16 cols
        floatx4 acc[4][4];
#pragma unroll
        for (int rg = 0; rg < 4; ++rg)
#pragma unroll
            for (int j = 0; j < 4; ++j)
                acc[rg][j] = (floatx4){0.f, 0.f, 0.f, 0.f};

#pragma unroll
        for (int ks = 0; ks < 16; ++ks) {
            half8 bf[4];
#pragma unroll
            for (int j = 0; j < 4; ++j) {
                int col = (ct0 + j) * 16 + l15;
                bf[j] = *(const half8*)(cbh + ((size_t)col << 9) + ks * 32 + quad * 8);
            }
            half8 af[4];
#pragma unroll
            for (int rg = 0; rg < 4; ++rg) {
                int r = half * 64 + rg * 16 + l15;
                int p = (ks * 4 + quad) ^ (r & 7);
                af[rg] = *(const half8*)(As + r * 512 + p * 8);
            }
#pragma unroll
            for (int rg = 0; rg < 4; ++rg)
#pragma unroll
                for (int j = 0; j < 4; ++j)
                    acc[rg][j] = __builtin_amdgcn_mfma_f32_16x16x32_f16(
                        af[rg], bf[j], acc[rg][j], 0, 0, 0);
        }
        // fold scores into per-lane top-2 (cols ascend: first-min tie-break preserved)
#pragma unroll
        for (int j = 0; j < 4; ++j) {
            int col = (ct0 + j) * 16 + l15;
            float cn = cnorm[col];
#pragma unroll
            for (int rg = 0; rg < 4; ++rg) {
#pragma unroll
                for (int reg = 0; reg < 4; ++reg) {
                    float s = fmaf(-2.0f, acc[rg][j][reg], cn);
                    int slot = rg * 4 + reg;
                    if (s < b1[slot]) { b2[slot] = b1[slot]; b1[slot] = s; i1[slot] = col; }
                    else if (s < b2[slot]) b2[slot] = s;
                }
            }
        }
    }

    // butterfly merge across the 16 col-lanes (l15) sharing each row
#pragma unroll
    for (int m = 1; m < 16; m <<= 1) {
#pragma unroll
        for (int s = 0; s < 16; ++s) {
            float ob1 = __shfl_xor(b1[s], m, 64);
            float ob2 = __shfl_xor(b2[s], m, 64);
            int   oi1 = __shfl_xor(i1[s], m, 64);
            if (ob1 < b1[s] || (ob1 == b1[s] && oi1 < i1[s])) {
                b2[s] = fminf(b1[s], ob2);
                b1[s] = ob1; i1[s] = oi1;
            } else {
                b2[s] = fminf(b2[s], ob1);
            }
        }
    }

    __syncthreads();   // done with As; reuse smem for cross-wave merge
    float* mb1 = (float*)smem;             // [4 wq][128 rows]
    float* mb2 = mb1 + 512;
    int*   mi1 = (int*)(mb2 + 512);
    if (l15 == 0) {
#pragma unroll
        for (int s = 0; s < 16; ++s) {
            int row = half * 64 + (s >> 2) * 16 + quad * 4 + (s & 3);
            mb1[wq * 128 + row] = b1[s];
            mb2[wq * 128 + row] = b2[s];
            mi1[wq * 128 + row] = i1[s];
        }
    }
    __syncthreads();
    if (tid < 128) {
        float r1 = mb1[tid], r2 = mb2[tid]; int ri = mi1[tid];
#pragma unroll
        for (int w = 1; w < 4; ++w) {
            float c1 = mb1[w * 128 + tid], c2 = mb2[w * 128 + tid]; int ci = mi1[w * 128 + tid];
            if (c1 < r1 || (c1 == r1 && ci < ri)) { r2 = fminf(r1, c2); r1 = c1; ri = ci; }
            else r2 = fminf(r2, c1);
        }
        int n = row0 + tid;
        indices[n] = ri;
        result[n] = 0xFFFFFFFFFFFFFFFFull;
        int f = (r2 - r1 < MARGIN) ? 1 : 0;
        flags[n] = f;
        if (f) { int pos = atomicAdd(count, 1); list[pos] = n; }
    }
}

// ---------------- exact fp32 rescan for flagged rows: 32 parts/row, 1 cb row/thread ----------------
__global__ __launch_bounds__(256) void repair3_kernel(
    const float* __restrict__ x, const float* __restrict__ cb,
    const float* __restrict__ cnorm, const int* __restrict__ list,
    const int* __restrict__ count, unsigned long long* __restrict__ result) {
    __shared__ float xrow[512];
    __shared__ unsigned long long red[256];
    const int tid = threadIdx.x;
    const int slot0 = blockIdx.x >> 5;   // / RPARTS
    const int part  = blockIdx.x & 31;   // % RPARTS
    const int cnt = *count;
    for (int slot = slot0; slot < cnt; slot += (RGRID / RPARTS)) {
        int n = list[slot];
        __syncthreads();   // prev iter's xrow/red reads done
        for (int t = tid; t < 512; t += 256) xrow[t] = x[(size_t)n * 512 + t];
        __syncthreads();
        int k = part * RROWS + tid;
        const float* crow = cb + (size_t)k * 512;
        float d0 = 0.f, d1 = 0.f, d2 = 0.f, d3 = 0.f;
        for (int t = 0; t < 512; t += 16) {
            float4 c0 = *(const float4*)(crow + t);
            float4 c1 = *(const float4*)(crow + t + 4);
            float4 c2 = *(const float4*)(crow + t + 8);
            float4 c3 = *(const float4*)(crow + t + 12);
            d0 = fmaf(c0.x, xrow[t+0], d0);  d0 = fmaf(c0.y, xrow[t+1], d0);
            d0 = fmaf(c0.z, xrow[t+2], d0);  d0 = fmaf(c0.w, xrow[t+3], d0);
            d1 = fmaf(c1.x, xrow[t+4], d1);  d1 = fmaf(c1.y, xrow[t+5], d1);
            d1 = fmaf(c1.z, xrow[t+6], d1);  d1 = fmaf(c1.w, xrow[t+7], d1);
            d2 = fmaf(c2.x, xrow[t+8], d2);  d2 = fmaf(c2.y, xrow[t+9], d2);
            d2 = fmaf(c2.z, xrow[t+10], d2); d2 = fmaf(c2.w, xrow[t+11], d2);
            d3 = fmaf(c3.x, xrow[t+12], d3); d3 = fmaf(c3.y, xrow[t+13], d3);
            d3 = fmaf(c3.z, xrow[t+14], d3); d3 = fmaf(c3.w, xrow[t+15], d3);
        }
        float s = cnorm[k] - 2.f * ((d0 + d1) + (d2 + d3));
        // pack (ordered score bits, index): u64 min == (min score, then min index)
        unsigned int sb = __float_as_uint(s);
        sb = (sb & 0x80000000u) ? ~sb : (sb | 0x80000000u);
        red[tid] = ((unsigned long long)sb << 32) | (unsigned int)k;
        __syncthreads();
        for (int st = 128; st > 0; st >>= 1) {
            if (tid < st) { if (red[tid + st] < red[tid]) red[tid] = red[tid + st]; }
            __syncthreads();
        }
        if (tid == 0) atomicMin(&result[n], red[0]);
    }
}

// ---------------- apply repaired indices ----------------
__global__ __launch_bounds__(256) void fixup_kernel(
    const int* __restrict__ flags, const unsigned long long* __restrict__ result,
    int* __restrict__ indices) {
    int n = blockIdx.x * 256 + threadIdx.x;
    if (flags[n]) indices[n] = (int)(result[n] & 0xFFFFFFFFu);
}

// ---------------- fallback fp32 argmin (used only if ws too small) ----------------
__global__ void cnorm_kernel(const float* __restrict__ cb, float* __restrict__ cnorm) {
    int wave = (blockIdx.x * blockDim.x + threadIdx.x) >> 6;
    int lane = threadIdx.x & 63;
    if (wave >= KCB) return;
    const float* row = cb + (size_t)wave * DDIM;
    float s = 0.f;
#pragma unroll
    for (int j = 0; j < DDIM / 64; ++j) { float v = row[lane + 64 * j]; s += v * v; }
#pragma unroll
    for (int off = 32; off > 0; off >>= 1) s += __shfl_down(s, off, 64);
    if (lane == 0) cnorm[wave] = s;
}

#define FBN 64
#define FBD 32
#define FLDA (FBN + 4)
__global__ __launch_bounds__(256) void argmin_fp32_kernel(
    const float* __restrict__ x, const float* __restrict__ cb,
    const float* __restrict__ cnorm, int* __restrict__ indices) {
    __shared__ float As[FBD][FLDA];
    __shared__ float Bs[FBD][FLDA];
    __shared__ float redv[FBN][16];
    __shared__ int   redi[FBN][16];
    const int tid = threadIdx.x;
    const int tx = tid & 15, ty = tid >> 4;
    const int row0 = blockIdx.x * FBN;
    float best[4]; int bidx[4];
#pragma unroll
    for (int i = 0; i < 4; ++i) { best[i] = 3.402823466e+38f; bidx[i] = KCB; }
    for (int k0 = 0; k0 < KCB; k0 += 64) {
        float acc[4][4] = {};
        for (int d0 = 0; d0 < DDIM; d0 += FBD) {
#pragma unroll
            for (int t = 0; t < 2; ++t) {
                int q = tid + t * 256, rr = q >> 3, dq = q & 7;
                float4 v = *(const float4*)(x + (size_t)(row0 + rr) * DDIM + d0 + dq * 4);
                As[dq*4+0][rr] = v.x; As[dq*4+1][rr] = v.y; As[dq*4+2][rr] = v.z; As[dq*4+3][rr] = v.w;
                float4 w = *(const float4*)(cb + (size_t)(k0 + rr) * DDIM + d0 + dq * 4);
                Bs[dq*4+0][rr] = w.x; Bs[dq*4+1][rr] = w.y; Bs[dq*4+2][rr] = w.z; Bs[dq*4+3][rr] = w.w;
            }
            __syncthreads();
#pragma unroll
            for (int d = 0; d < FBD; ++d) {
                float4 av = *(const float4*)&As[d][ty * 4];
                float4 bv = *(const float4*)&Bs[d][tx * 4];
                float a[4] = {av.x, av.y, av.z, av.w}, b[4] = {bv.x, bv.y, bv.z, bv.w};
#pragma unroll
                for (int i = 0; i < 4; ++i)
#pragma unroll
                    for (int j = 0; j < 4; ++j) acc[i][j] += a[i] * b[j];
            }
            __syncthreads();
        }
#pragma unroll
        for (int j = 0; j < 4; ++j) {
            int k = k0 + tx * 4 + j;
            float cn = cnorm[k];
#pragma unroll
            for (int i = 0; i < 4; ++i) {
                float s = cn - 2.0f * acc[i][j];
                if (s < best[i] || (s == best[i] && k < bidx[i])) { best[i] = s; bidx[i] = k; }
            }
        }
    }
#pragma unroll
    for (int i = 0; i < 4; ++i) { redv[ty*4+i][tx] = best[i]; redi[ty*4+i][tx] = bidx[i]; }
    __syncthreads();
    if (tid < FBN) {
        float bv = redv[tid][0]; int bi = redi[tid][0];
#pragma unroll
        for (int t = 1; t < 16; ++t) {
            float v = redv[tid][t]; int ii = redi[tid][t];
            if (v < bv || (v == bv && ii < bi)) { bv = v; bi = ii; }
        }
        indices[row0 + tid] = bi;
    }
}

// ---------------- gather + straight-through output + loss ----------------
__global__ __launch_bounds__(256) void output_kernel(
    const float* __restrict__ x, const float* __restrict__ cb,
    const int* __restrict__ indices, float* __restrict__ out,
    float* __restrict__ loss_acc) {
    size_t base = ((size_t)blockIdx.x * blockDim.x + threadIdx.x) * 16;
    int n = (int)(base >> 9);
    int d = (int)(base & 511);
    int idx = indices[n];
    const float* cr = cb + (size_t)idx * DDIM + d;
    const float* xr = x + base;
    float* orow = out + base;
    float lsum = 0.f;
#pragma unroll
    for (int t = 0; t < 4; ++t) {
        float4 q  = *(const float4*)(cr + t * 4);
        float4 xv = *(const float4*)(xr + t * 4);
        float dx0 = q.x - xv.x, dx1 = q.y - xv.y, dx2 = q.z - xv.z, dx3 = q.w - xv.w;
        float4 o;
        o.x = xv.x + dx0; o.y = xv.y + dx1; o.z = xv.z + dx2; o.w = xv.w + dx3;
        *(float4*)(orow + t * 4) = o;
        lsum += dx0*dx0 + dx1*dx1 + dx2*dx2 + dx3*dx3;
    }
#pragma unroll
    for (int off = 32; off > 0; off >>= 1) lsum += __shfl_down(lsum, off, 64);
    __shared__ float wsum[4];
    int lane = threadIdx.x & 63, wv = threadIdx.x >> 6;
    if (lane == 0) wsum[wv] = lsum;
    __syncthreads();
    if (threadIdx.x == 0) atomicAdd(loss_acc, wsum[0] + wsum[1] + wsum[2] + wsum[3]);
}

__global__ void finalize_kernel(const float* __restrict__ loss_acc, float* __restrict__ out_loss) {
    *out_loss = (*loss_acc) * (0.25f / (float)((size_t)N_TOT * DDIM));
}

extern "C" void kernel_launch(void* const* d_in, const int* in_sizes, int n_in,
                              void* d_out, int out_size, void* d_ws, size_t ws_size,
                              hipStream_t stream) {
    const float* x  = (const float*)d_in[0];
    const float* cb = (const float*)d_in[1];
    float* out = (float*)d_out;

    char* ws = (char*)d_ws;
    float* loss_acc = (float*)ws;                                 // 4 B
    int*   count    = (int*)(ws + 8);                             // 4 B
    int*   indices  = (int*)(ws + 256);                           // 128 KiB
    int*   flags    = (int*)(ws + 256 + 131072);                  // 128 KiB
    float* cnorm    = (float*)(ws + 256 + 2 * 131072);            // 32 KiB
    int*   list     = (int*)(ws + 256 + 2 * 131072 + 32768);      // 128 KiB
    unsigned long long* result =
        (unsigned long long*)(ws + 256 + 3 * 131072 + 32768);     // 256 KiB
    size_t off = 256 + 3 * 131072 + 32768 + 262144;               // ~0.69 MiB, 256-aligned
    _Float16* xh  = (_Float16*)(ws + off);                        // 32 MiB
    _Float16* cbh = (_Float16*)(ws + off + (size_t)N_TOT * DDIM * 2);  // 8 MiB
    size_t need = off + (size_t)N_TOT * DDIM * 2 + (size_t)KCB * DDIM * 2;

    hipMemsetAsync(ws, 0, 16, stream);   // loss_acc + count
    if (ws_size >= need) {
        convert_x_kernel<<<(N_TOT * DDIM) / (256 * 8), 256, 0, stream>>>(x, xh);
        convert_cb_kernel<<<KCB / 4, 256, 0, stream>>>(cb, cbh, cnorm);
        gemm_topk_kernel<<<N_TOT / GBN, 512, 0, stream>>>(xh, cbh, cnorm, indices, flags,
                                                          list, count, result);
        repair3_kernel<<<RGRID, 256, 0, stream>>>(x, cb, cnorm, list, count, result);
        fixup_kernel<<<N_TOT / 256, 256, 0, stream>>>(flags, result, indices);
    } else {
        cnorm_kernel<<<KCB / 4, 256, 0, stream>>>(cb, cnorm);
        argmin_fp32_kernel<<<N_TOT / FBN, 256, 0, stream>>>(x, cb, cnorm, indices);
    }
    output_kernel<<<((size_t)N_TOT * DDIM) / (256 * 16), 256, 0, stream>>>(
        x, cb, indices, out, loss_acc);
    finalize_kernel<<<1, 1, 0, stream>>>(loss_acc, out + (size_t)N_TOT * DDIM);
}